// Round 3
// baseline (202.592 us; speedup 1.0000x reference)
//
#include <hip/hip_runtime.h>
#include <stdint.h>

#define TB 2048
#define DM 256

typedef __attribute__((ext_vector_type(4))) float f32x4;
typedef __attribute__((ext_vector_type(8))) short short8;

__device__ __forceinline__ unsigned short f2bf(float f) {
  union { float f; unsigned u; } v; v.f = f;
  unsigned r = v.u + 0x7fffu + ((v.u >> 16) & 1u);
  return (unsigned short)(r >> 16);
}
__device__ __forceinline__ unsigned pack2(float a, float b) {
  return (unsigned)f2bf(a) | ((unsigned)f2bf(b) << 16);
}

// ---------------- kernel 1: decay table ----------------
__global__ void k_tables(const float* __restrict__ eta, const float* __restrict__ beta,
                         const float* __restrict__ alpha, float* __restrict__ td) {
  int i = blockIdx.x * 256 + threadIdx.x;
  if (i < TB) {
    float ab = fabsf(beta[0]);
    float dt = powf((float)i, ab);
    td[i] = alpha[0] * eta[0] / (1.0f + dt) * 0.17677669529663687f;
  }
}

// ---------------- kernel 2: QKV projection ----------------
__global__ __launch_bounds__(256, 2) void k_proj(
    const float* __restrict__ x,
    const float* __restrict__ Wq, const float* __restrict__ bq,
    const float* __restrict__ Wk, const float* __restrict__ bk,
    const float* __restrict__ Wv, const float* __restrict__ bv,
    unsigned short* __restrict__ Qb, unsigned short* __restrict__ Kb,
    unsigned short* __restrict__ Vtb) {
  __shared__ unsigned short Al[64 * 256];
  __shared__ unsigned short Bl[64 * 256];
  const int m0 = blockIdx.x * 64, n0 = blockIdx.y * 64, z = blockIdx.z;
  const int tid = threadIdx.x;
  const float* W = (z == 0) ? Wq : (z == 1) ? Wk : Wv;
  const float* bias = (z == 0) ? bq : (z == 1) ? bk : bv;

#pragma unroll
  for (int it = 0; it < 8; ++it) {
    int C = it * 256 + tid;
    int row = C >> 5, lc = C & 31;
    const float4* ga = (const float4*)(x + (size_t)(m0 + row) * 256 + lc * 8);
    float4 a0 = ga[0], a1 = ga[1];
    uint4 pa;
    pa.x = pack2(a0.x, a0.y); pa.y = pack2(a0.z, a0.w);
    pa.z = pack2(a1.x, a1.y); pa.w = pack2(a1.z, a1.w);
    *(uint4*)&Al[row * 256 + ((lc ^ (row & 7)) * 8)] = pa;
    const float4* gb = (const float4*)(W + (size_t)(n0 + row) * 256 + lc * 8);
    float4 b0 = gb[0], b1 = gb[1];
    uint4 pb;
    pb.x = pack2(b0.x, b0.y); pb.y = pack2(b0.z, b0.w);
    pb.z = pack2(b1.x, b1.y); pb.w = pack2(b1.z, b1.w);
    *(uint4*)&Bl[row * 256 + ((lc ^ (row & 7)) * 8)] = pb;
  }
  __syncthreads();

  const int w = tid >> 6, l = tid & 63, g = l >> 4, ql = l & 15;
  const int wm = w >> 1, wn = w & 1;
  f32x4 acc[2][2] = {};
#pragma unroll
  for (int kk = 0; kk < 8; ++kk) {
    short8 af[2], bf_[2];
#pragma unroll
    for (int mi = 0; mi < 2; ++mi) {
      int row = wm * 32 + mi * 16 + ql;
      af[mi] = *(const short8*)&Al[row * 256 + (((kk * 4 + g) ^ (row & 7)) * 8)];
    }
#pragma unroll
    for (int ni = 0; ni < 2; ++ni) {
      int row = wn * 32 + ni * 16 + ql;
      bf_[ni] = *(const short8*)&Bl[row * 256 + (((kk * 4 + g) ^ (row & 7)) * 8)];
    }
#pragma unroll
    for (int mi = 0; mi < 2; ++mi)
#pragma unroll
      for (int ni = 0; ni < 2; ++ni)
        acc[mi][ni] = __builtin_amdgcn_mfma_f32_16x16x32_bf16(af[mi], bf_[ni], acc[mi][ni], 0, 0, 0);
  }

#pragma unroll
  for (int ni = 0; ni < 2; ++ni) {
    int n = n0 + wn * 32 + ni * 16 + ql;
    float bs = bias[n];
#pragma unroll
    for (int mi = 0; mi < 2; ++mi) {
      int mb = m0 + wm * 32 + mi * 16 + 4 * g;
      f32x4 v = acc[mi][ni];
      v.x += bs; v.y += bs; v.z += bs; v.w += bs;
      if (z == 2) {
        int batch = mb >> 11, t = mb & 2047;
        uint2 pv; pv.x = pack2(v.x, v.y); pv.y = pack2(v.z, v.w);
        *(uint2*)&Vtb[(size_t)(batch * 256 + n) * 2048 + t] = pv;
      } else {
        unsigned short* dst = (z == 0) ? Qb : Kb;
        dst[(size_t)(mb + 0) * 256 + n] = f2bf(v.x);
        dst[(size_t)(mb + 1) * 256 + n] = f2bf(v.y);
        dst[(size_t)(mb + 2) * 256 + n] = f2bf(v.z);
        dst[(size_t)(mb + 3) * 256 + n] = f2bf(v.w);
      }
    }
  }
}

// ---------------- kernel 3: fused causal attention with prior ----------------
// Balanced pairing: block i handles q-tiles (i, 127-i), QB=16 rows each.
// grid (64 pairs, 4 batches, 2 head-groups), 256 threads = 4 waves = 4 heads.
// Every block executes exactly 33 k-steps total. 44KB LDS -> 2 blocks/CU.
__global__ __launch_bounds__(256, 2) void k_attn(
    const unsigned short* __restrict__ Qb, const unsigned short* __restrict__ Kb,
    const unsigned short* __restrict__ Vtb, const float* __restrict__ oc,
    const float* __restrict__ td, unsigned short* __restrict__ Ab) {
  __shared__ unsigned short Kl[64 * 128];   // 16KB  K slice [k][hg's 128 dims]
  __shared__ unsigned short Vl[128 * 64];   // 16KB  V^T slice [dim][k]
  __shared__ unsigned short Pl[4][16 * 64]; // 8KB   per-wave P [q][k]
  __shared__ float Pr[16 * 64];             // 4KB   prior [q][k] f32
  const int pairi = blockIdx.x, bb = blockIdx.y, hg = blockIdx.z;
  const int tid = threadIdx.x;
  const int w = tid >> 6, l = tid & 63, g = l >> 4, ql = l & 15;
  const int h = hg * 4 + w;          // global head
  const int dbase = hg * 128;        // column base of this head-group's slice
  const f32x4 zero4 = {0.f, 0.f, 0.f, 0.f};

  // staging lane mapping (constant across steps)
  const int krow_b = tid >> 4, klc = tid & 15;   // K: 16 chunks/row
  const int vrow_b = tid >> 3, vlc = tid & 7;    // V: 8 chunks/row
  uint4 rK[4], rV[4];

#pragma unroll 1
  for (int pass = 0; pass < 2; ++pass) {
    const int qt = pass ? (127 - pairi) : pairi;
    const int q0 = qt * 16;
    const int nst = (q0 + 79) >> 6;   // k-tiles covering k <= q0+15

    short8 qf = *(const short8*)&Qb[(size_t)(bb * TB + q0 + ql) * 256 + h * 32 + 8 * g];

    const int pq = tid & 15, pck = tid >> 4;  // prior: q-row, k-chunk(4 wide)
    const float oq0 = oc[(size_t)(bb * TB + q0 + pq) * 3 + 0];
    const float oq1 = oc[(size_t)(bb * TB + q0 + pq) * 3 + 1];
    const float oq2 = oc[(size_t)(bb * TB + q0 + pq) * 3 + 2];

    f32x4 oacc[2] = {};
    float mrow = -__builtin_inff(), srow = 0.f;

    // prologue: issue step-0 loads (overlaps previous pass epilogue)
#pragma unroll
    for (int it = 0; it < 4; ++it) {
      int krow = it * 16 + krow_b;
      rK[it] = *(const uint4*)&Kb[(size_t)(bb * TB + 0 + krow) * 256 + dbase + klc * 8];
      int vrow = it * 32 + vrow_b;
      rV[it] = *(const uint4*)&Vtb[(size_t)(bb * 256 + dbase + vrow) * 2048 + 0 + vlc * 8];
    }

    for (int st = 0; st < nst; ++st) {
      const int k0 = st * 64;
      __syncthreads();   // previous step's LDS reads complete
      // write staged regs -> LDS (vmcnt wait inserted by compiler)
#pragma unroll
      for (int it = 0; it < 4; ++it) {
        int krow = it * 16 + krow_b;
        *(uint4*)&Kl[krow * 128 + ((klc ^ (krow & 7)) * 8)] = rK[it];
        int vrow = it * 32 + vrow_b;
        *(uint4*)&Vl[vrow * 64 + ((vlc ^ (vrow & 7)) * 8)] = rV[it];
      }
      // prior tile [16 q][64 k]
      {
        float pv[4];
#pragma unroll
        for (int j = 0; j < 4; ++j) {
          int kg = k0 + pck * 4 + j;
          float d0 = oq0 - oc[(size_t)(bb * TB + kg) * 3 + 0];
          float d1 = oq1 - oc[(size_t)(bb * TB + kg) * 3 + 1];
          float d2 = oq2 - oc[(size_t)(bb * TB + kg) * 3 + 2];
          float dist = d0 * d0 + d1 * d1 + d2 * d2;
          int dd = (q0 + pq) - kg; dd = dd < 0 ? -dd : dd;
          pv[j] = td[dd] * __expf(-dist);
        }
        f32x4 pvv = {pv[0], pv[1], pv[2], pv[3]};
        *(f32x4*)&Pr[pq * 64 + ((pck ^ pq) * 4)] = pvv;
      }
      __syncthreads();   // staging + prior visible
      // prefetch next step (latency hides under compute below)
      if (st + 1 < nst) {
        const int kn = k0 + 64;
#pragma unroll
        for (int it = 0; it < 4; ++it) {
          int krow = it * 16 + krow_b;
          rK[it] = *(const uint4*)&Kb[(size_t)(bb * TB + kn + krow) * 256 + dbase + klc * 8];
          int vrow = it * 32 + vrow_b;
          rV[it] = *(const uint4*)&Vtb[(size_t)(bb * 256 + dbase + vrow) * 2048 + kn + vlc * 8];
        }
      }

      // ---- S^T = mfma(K, Q): lane owns q=ql, k = 16*kb+4*g+reg ----
      short8 kf[4];
#pragma unroll
      for (int kb = 0; kb < 4; ++kb) {
        int row = kb * 16 + ql;
        kf[kb] = *(const short8*)&Kl[row * 128 + (((w * 4 + g) ^ (row & 7)) * 8)];
      }
      f32x4 s[4];
#pragma unroll
      for (int kb = 0; kb < 4; ++kb)
        s[kb] = __builtin_amdgcn_mfma_f32_16x16x32_bf16(kf[kb], qf, zero4, 0, 0, 0);

      const bool diag = (k0 + 64 > q0);
      const int qg = q0 + ql;
      float mt_ = -__builtin_inff();
#pragma unroll
      for (int kb = 0; kb < 4; ++kb) {
        f32x4 pr = *(const f32x4*)&Pr[ql * 64 + (((kb * 4 + g) ^ ql) * 4)];
        s[kb].x *= pr.x; s[kb].y *= pr.y; s[kb].z *= pr.z; s[kb].w *= pr.w;
        if (diag) {
          int kbase = k0 + kb * 16 + 4 * g;
          if (kbase + 0 > qg) s[kb].x = -__builtin_inff();
          if (kbase + 1 > qg) s[kb].y = -__builtin_inff();
          if (kbase + 2 > qg) s[kb].z = -__builtin_inff();
          if (kbase + 3 > qg) s[kb].w = -__builtin_inff();
        }
        mt_ = fmaxf(mt_, fmaxf(fmaxf(s[kb].x, s[kb].y), fmaxf(s[kb].z, s[kb].w)));
      }
      mt_ = fmaxf(mt_, __shfl_xor(mt_, 16));
      mt_ = fmaxf(mt_, __shfl_xor(mt_, 32));
      float mn = fmaxf(mrow, mt_);
      float scale = __expf(mrow - mn);
      mrow = mn;
      float ssum = 0.f;
#pragma unroll
      for (int kb = 0; kb < 4; ++kb) {
        f32x4 p;
        p.x = __expf(s[kb].x - mn); p.y = __expf(s[kb].y - mn);
        p.z = __expf(s[kb].z - mn); p.w = __expf(s[kb].w - mn);
        ssum += (p.x + p.y) + (p.z + p.w);
        uint2 pp; pp.x = pack2(p.x, p.y); pp.y = pack2(p.z, p.w);
        int c16 = 2 * kb + (g >> 1);
        *(uint2*)&Pl[w][ql * 64 + ((c16 ^ (ql & 7)) * 8) + (g & 1) * 4] = pp;
      }
      srow = srow * scale + ssum;
#pragma unroll
      for (int db = 0; db < 2; ++db) {
        oacc[db].x *= scale; oacc[db].y *= scale;
        oacc[db].z *= scale; oacc[db].w *= scale;
      }
      // this wave's P writes -> visible to its own cross-lane reads
      asm volatile("s_waitcnt lgkmcnt(0)" ::: "memory");

      // ---- PV: O^T[d][q] += sum_k V^T[d][k] * P[q][k] ----
#pragma unroll
      for (int ks = 0; ks < 2; ++ks) {
        short8 vf[2], pf;
        pf = *(const short8*)&Pl[w][ql * 64 + (((ks * 4 + g) ^ (ql & 7)) * 8)];
#pragma unroll
        for (int db = 0; db < 2; ++db) {
          int row = w * 32 + db * 16 + ql;
          vf[db] = *(const short8*)&Vl[row * 64 + (((ks * 4 + g) ^ (row & 7)) * 8)];
        }
#pragma unroll
        for (int db = 0; db < 2; ++db)
          oacc[db] = __builtin_amdgcn_mfma_f32_16x16x32_bf16(vf[db], pf, oacc[db], 0, 0, 0);
      }
    }

    // ---- epilogue: normalize, store attn-out bf16 ----
    float s_ = srow;
    s_ += __shfl_xor(s_, 16);
    s_ += __shfl_xor(s_, 32);
    float rinv = 1.0f / s_;
#pragma unroll
    for (int db = 0; db < 2; ++db) {
      f32x4 v = oacc[db];
      uint2 pv2;
      pv2.x = pack2(v.x * rinv, v.y * rinv);
      pv2.y = pack2(v.z * rinv, v.w * rinv);
      *(uint2*)&Ab[(size_t)(bb * TB + q0 + ql) * 256 + h * 32 + db * 16 + 4 * g] = pv2;
    }
  }
}

// ---------------- kernel 4: output projection ----------------
__global__ __launch_bounds__(256, 2) void k_oproj(
    const unsigned short* __restrict__ Ab, const float* __restrict__ Wo,
    const float* __restrict__ bo, float* __restrict__ out) {
  __shared__ unsigned short Al[64 * 256];
  __shared__ unsigned short Bl[64 * 256];
  const int m0 = blockIdx.x * 64, n0 = blockIdx.y * 64;
  const int tid = threadIdx.x;
#pragma unroll
  for (int it = 0; it < 8; ++it) {
    int C = it * 256 + tid;
    int row = C >> 5, lc = C & 31;
    uint4 va = *(const uint4*)&Ab[(size_t)(m0 + row) * 256 + lc * 8];
    *(uint4*)&Al[row * 256 + ((lc ^ (row & 7)) * 8)] = va;
    const float4* gb = (const float4*)(Wo + (size_t)(n0 + row) * 256 + lc * 8);
    float4 b0 = gb[0], b1 = gb[1];
    uint4 pb;
    pb.x = pack2(b0.x, b0.y); pb.y = pack2(b0.z, b0.w);
    pb.z = pack2(b1.x, b1.y); pb.w = pack2(b1.z, b1.w);
    *(uint4*)&Bl[row * 256 + ((lc ^ (row & 7)) * 8)] = pb;
  }
  __syncthreads();

  const int w = tid >> 6, l = tid & 63, g = l >> 4, ql = l & 15;
  const int wm = w >> 1, wn = w & 1;
  f32x4 acc[2][2] = {};
#pragma unroll
  for (int kk = 0; kk < 8; ++kk) {
    short8 af[2], bf_[2];
#pragma unroll
    for (int mi = 0; mi < 2; ++mi) {
      int row = wm * 32 + mi * 16 + ql;
      af[mi] = *(const short8*)&Al[row * 256 + (((kk * 4 + g) ^ (row & 7)) * 8)];
    }
#pragma unroll
    for (int ni = 0; ni < 2; ++ni) {
      int row = wn * 32 + ni * 16 + ql;
      bf_[ni] = *(const short8*)&Bl[row * 256 + (((kk * 4 + g) ^ (row & 7)) * 8)];
    }
#pragma unroll
    for (int mi = 0; mi < 2; ++mi)
#pragma unroll
      for (int ni = 0; ni < 2; ++ni)
        acc[mi][ni] = __builtin_amdgcn_mfma_f32_16x16x32_bf16(af[mi], bf_[ni], acc[mi][ni], 0, 0, 0);
  }
#pragma unroll
  for (int ni = 0; ni < 2; ++ni) {
    int n = n0 + wn * 32 + ni * 16 + ql;
    float bs = bo[n];
#pragma unroll
    for (int mi = 0; mi < 2; ++mi) {
      int mb = m0 + wm * 32 + mi * 16 + 4 * g;
      out[(size_t)(mb + 0) * 256 + n] = acc[mi][ni].x + bs;
      out[(size_t)(mb + 1) * 256 + n] = acc[mi][ni].y + bs;
      out[(size_t)(mb + 2) * 256 + n] = acc[mi][ni].z + bs;
      out[(size_t)(mb + 3) * 256 + n] = acc[mi][ni].w + bs;
    }
  }
}

extern "C" void kernel_launch(void* const* d_in, const int* in_sizes, int n_in,
                              void* d_out, int out_size, void* d_ws, size_t ws_size,
                              hipStream_t stream) {
  const float* x    = (const float*)d_in[0];
  const float* oc   = (const float*)d_in[1];
  const float* Wq   = (const float*)d_in[2];
  const float* bq   = (const float*)d_in[3];
  const float* Wk   = (const float*)d_in[4];
  const float* bk   = (const float*)d_in[5];
  const float* Wv   = (const float*)d_in[6];
  const float* bv   = (const float*)d_in[7];
  const float* Wo   = (const float*)d_in[8];
  const float* bo   = (const float*)d_in[9];
  const float* eta  = (const float*)d_in[10];
  const float* beta = (const float*)d_in[11];
  const float* alpha= (const float*)d_in[12];

  unsigned short* Qb  = (unsigned short*)d_ws;
  unsigned short* Kb  = Qb + (size_t)8192 * 256;
  unsigned short* Vtb = Kb + (size_t)8192 * 256;
  unsigned short* Ab  = Vtb + (size_t)8192 * 256;
  float* td = (float*)(Ab + (size_t)8192 * 256);
  float* out = (float*)d_out;

  k_tables<<<dim3(8), dim3(256), 0, stream>>>(eta, beta, alpha, td);
  k_proj<<<dim3(128, 4, 3), dim3(256), 0, stream>>>(x, Wq, bq, Wk, bk, Wv, bv, Qb, Kb, Vtb);
  k_attn<<<dim3(64, 4, 2), dim3(256), 0, stream>>>(Qb, Kb, Vtb, oc, td, Ab);
  k_oproj<<<dim3(128, 4), dim3(256), 0, stream>>>(Ab, Wo, bo, out);
}

// Round 4
// 119.035 us; speedup vs baseline: 1.7020x; 1.7020x over previous
//
#include <hip/hip_runtime.h>
#include <stdint.h>

#define TB 2048
#define DM 256

typedef __attribute__((ext_vector_type(4))) float f32x4;
typedef __attribute__((ext_vector_type(8))) short short8;

__device__ __forceinline__ unsigned short f2bf(float f) {
  union { float f; unsigned u; } v; v.f = f;
  unsigned r = v.u + 0x7fffu + ((v.u >> 16) & 1u);
  return (unsigned short)(r >> 16);
}
__device__ __forceinline__ unsigned pack2(float a, float b) {
  return (unsigned)f2bf(a) | ((unsigned)f2bf(b) << 16);
}
__device__ __forceinline__ float bf2f(unsigned short u) {
  union { unsigned u; float f; } v; v.u = ((unsigned)u) << 16;
  return v.f;
}

// ---------------- kernel 1: decay table ----------------
__global__ void k_tables(const float* __restrict__ eta, const float* __restrict__ beta,
                         const float* __restrict__ alpha, float* __restrict__ td) {
  int i = blockIdx.x * 256 + threadIdx.x;
  if (i < TB) {
    float ab = fabsf(beta[0]);
    float dt = powf((float)i, ab);
    td[i] = alpha[0] * eta[0] / (1.0f + dt) * 0.17677669529663687f;
  }
}

// ---------------- kernel 2: QKV projection ----------------
__global__ __launch_bounds__(256, 2) void k_proj(
    const float* __restrict__ x,
    const float* __restrict__ Wq, const float* __restrict__ bq,
    const float* __restrict__ Wk, const float* __restrict__ bk,
    const float* __restrict__ Wv, const float* __restrict__ bv,
    unsigned short* __restrict__ Qb, unsigned short* __restrict__ Kb,
    unsigned short* __restrict__ Vtb) {
  __shared__ unsigned short Al[64 * 256];
  __shared__ unsigned short Bl[64 * 256];
  const int m0 = blockIdx.x * 64, n0 = blockIdx.y * 64, z = blockIdx.z;
  const int tid = threadIdx.x;
  const float* W = (z == 0) ? Wq : (z == 1) ? Wk : Wv;
  const float* bias = (z == 0) ? bq : (z == 1) ? bk : bv;

#pragma unroll
  for (int it = 0; it < 8; ++it) {
    int C = it * 256 + tid;
    int row = C >> 5, lc = C & 31;
    const float4* ga = (const float4*)(x + (size_t)(m0 + row) * 256 + lc * 8);
    float4 a0 = ga[0], a1 = ga[1];
    uint4 pa;
    pa.x = pack2(a0.x, a0.y); pa.y = pack2(a0.z, a0.w);
    pa.z = pack2(a1.x, a1.y); pa.w = pack2(a1.z, a1.w);
    *(uint4*)&Al[row * 256 + ((lc ^ (row & 7)) * 8)] = pa;
    const float4* gb = (const float4*)(W + (size_t)(n0 + row) * 256 + lc * 8);
    float4 b0 = gb[0], b1 = gb[1];
    uint4 pb;
    pb.x = pack2(b0.x, b0.y); pb.y = pack2(b0.z, b0.w);
    pb.z = pack2(b1.x, b1.y); pb.w = pack2(b1.z, b1.w);
    *(uint4*)&Bl[row * 256 + ((lc ^ (row & 7)) * 8)] = pb;
  }
  __syncthreads();

  const int w = tid >> 6, l = tid & 63, g = l >> 4, ql = l & 15;
  const int wm = w >> 1, wn = w & 1;
  f32x4 acc[2][2] = {};
#pragma unroll
  for (int kk = 0; kk < 8; ++kk) {
    short8 af[2], bf_[2];
#pragma unroll
    for (int mi = 0; mi < 2; ++mi) {
      int row = wm * 32 + mi * 16 + ql;
      af[mi] = *(const short8*)&Al[row * 256 + (((kk * 4 + g) ^ (row & 7)) * 8)];
    }
#pragma unroll
    for (int ni = 0; ni < 2; ++ni) {
      int row = wn * 32 + ni * 16 + ql;
      bf_[ni] = *(const short8*)&Bl[row * 256 + (((kk * 4 + g) ^ (row & 7)) * 8)];
    }
#pragma unroll
    for (int mi = 0; mi < 2; ++mi)
#pragma unroll
      for (int ni = 0; ni < 2; ++ni)
        acc[mi][ni] = __builtin_amdgcn_mfma_f32_16x16x32_bf16(af[mi], bf_[ni], acc[mi][ni], 0, 0, 0);
  }

#pragma unroll
  for (int ni = 0; ni < 2; ++ni) {
    int n = n0 + wn * 32 + ni * 16 + ql;
    float bs = bias[n];
#pragma unroll
    for (int mi = 0; mi < 2; ++mi) {
      int mb = m0 + wm * 32 + mi * 16 + 4 * g;
      f32x4 v = acc[mi][ni];
      v.x += bs; v.y += bs; v.z += bs; v.w += bs;
      if (z == 2) {
        int batch = mb >> 11, t = mb & 2047;
        uint2 pv; pv.x = pack2(v.x, v.y); pv.y = pack2(v.z, v.w);
        *(uint2*)&Vtb[(size_t)(batch * 256 + n) * 2048 + t] = pv;
      } else {
        unsigned short* dst = (z == 0) ? Qb : Kb;
        dst[(size_t)(mb + 0) * 256 + n] = f2bf(v.x);
        dst[(size_t)(mb + 1) * 256 + n] = f2bf(v.y);
        dst[(size_t)(mb + 2) * 256 + n] = f2bf(v.z);
        dst[(size_t)(mb + 3) * 256 + n] = f2bf(v.w);
      }
    }
  }
}

// ---------------- kernel 3: fused causal attention with prior ----------------
// QB=32, 512 threads = 8 waves = 8 heads. K/V fragments loaded DIRECTLY from
// global (no LDS staging; each wave only touches its own head's slice).
// LDS: Pl (P transpose, per wave) + Pr (shared prior tile) = 40KB -> 2 blocks/CU.
// NHALF=2: split-K halves write (unnormalized O bf16, m, s) partials; k_merge
// combines. Blocks dispatched longest-first (qt descending) for LPT balance.
template <int NHALF>
__global__ __launch_bounds__(512, 4) void k_attn(
    const unsigned short* __restrict__ Qb, const unsigned short* __restrict__ Kb,
    const unsigned short* __restrict__ Vtb, const float* __restrict__ oc,
    const float* __restrict__ td, unsigned short* __restrict__ Op,
    float2* __restrict__ MS, unsigned short* __restrict__ Ab) {
  __shared__ unsigned short Pl[8][32 * 64]; // 32KB per-wave P [q][k]
  __shared__ float Pr[32 * 64];             // 8KB  prior [q][k]
  const int bx = blockIdx.x, bb = blockIdx.y;
  const int qt = (NHALF == 2) ? (63 - (bx >> 1)) : (63 - bx);
  const int half = (NHALF == 2) ? (bx & 1) : 0;
  const int q0 = qt * 32;
  const int nst = (qt + 2) >> 1;
  const int nh0 = (NHALF == 2) ? ((nst + 1) >> 1) : nst;
  const int s_begin = (half == 0) ? 0 : nh0;
  const int s_end = (half == 0) ? nh0 : nst;
  const int tid = threadIdx.x;
  const int w = tid >> 6, l = tid & 63, g = l >> 4, ql = l & 15;
  const int h = w;
  const f32x4 zero4 = {0.f, 0.f, 0.f, 0.f};

  // Q fragments (held in regs all block)
  short8 qf[2];
#pragma unroll
  for (int qb = 0; qb < 2; ++qb)
    qf[qb] = *(const short8*)&Qb[(size_t)(bb * TB + q0 + qb * 16 + ql) * 256 + h * 32 + 8 * g];

  // prior q-side oc for this thread's row
  const int pq = tid & 31, pck = tid >> 5;  // pck in [0,16)
  const float oq0 = oc[(size_t)(bb * TB + q0 + pq) * 3 + 0];
  const float oq1 = oc[(size_t)(bb * TB + q0 + pq) * 3 + 1];
  const float oq2 = oc[(size_t)(bb * TB + q0 + pq) * 3 + 2];

  f32x4 oacc[2][2] = {};
  float mrow[2] = {-__builtin_inff(), -__builtin_inff()};
  float srow[2] = {0.f, 0.f};

  for (int st = s_begin; st < s_end; ++st) {
    const int k0 = st * 64;
    // K fragments: direct global loads, issued before barriers (latency hides
    // under prior compute + other block's work)
    short8 kf[4];
#pragma unroll
    for (int kb = 0; kb < 4; ++kb)
      kf[kb] = *(const short8*)&Kb[(size_t)(bb * TB + k0 + kb * 16 + ql) * 256 + h * 32 + 8 * g];

    // prior tile [32 q][64 k], computed once, shared by all 8 heads
    float pv[4];
#pragma unroll
    for (int j = 0; j < 4; ++j) {
      int kg = k0 + pck * 4 + j;
      float d0 = oq0 - oc[(size_t)(bb * TB + kg) * 3 + 0];
      float d1 = oq1 - oc[(size_t)(bb * TB + kg) * 3 + 1];
      float d2 = oq2 - oc[(size_t)(bb * TB + kg) * 3 + 2];
      float dist = d0 * d0 + d1 * d1 + d2 * d2;
      int dd = (q0 + pq) - kg; dd = dd < 0 ? -dd : dd;
      pv[j] = td[dd] * __expf(-dist);
    }
    __syncthreads();  // prev step's Pr readers done
    {
      f32x4 pvv = {pv[0], pv[1], pv[2], pv[3]};
      *(f32x4*)&Pr[pq * 64 + ((pck ^ (pq & 15)) * 4)] = pvv;
    }
    __syncthreads();  // Pr visible

    // ---- S^T = mfma(K, Q): lane owns q = qb*16+ql, k = 16*kb+4*g+reg ----
    const bool diag = (k0 + 64 > q0);
#pragma unroll
    for (int qb = 0; qb < 2; ++qb) {
      const int qq = qb * 16 + ql;
      const int qg = q0 + qq;
      f32x4 s[4];
#pragma unroll
      for (int kb = 0; kb < 4; ++kb)
        s[kb] = __builtin_amdgcn_mfma_f32_16x16x32_bf16(kf[kb], qf[qb], zero4, 0, 0, 0);
      float mt_ = -__builtin_inff();
#pragma unroll
      for (int kb = 0; kb < 4; ++kb) {
        f32x4 pr = *(const f32x4*)&Pr[qq * 64 + (((kb * 4 + g) ^ ql) * 4)];
        s[kb].x *= pr.x; s[kb].y *= pr.y; s[kb].z *= pr.z; s[kb].w *= pr.w;
        if (diag) {
          int kbase = k0 + kb * 16 + 4 * g;
          if (kbase + 0 > qg) s[kb].x = -__builtin_inff();
          if (kbase + 1 > qg) s[kb].y = -__builtin_inff();
          if (kbase + 2 > qg) s[kb].z = -__builtin_inff();
          if (kbase + 3 > qg) s[kb].w = -__builtin_inff();
        }
        mt_ = fmaxf(mt_, fmaxf(fmaxf(s[kb].x, s[kb].y), fmaxf(s[kb].z, s[kb].w)));
      }
      mt_ = fmaxf(mt_, __shfl_xor(mt_, 16));
      mt_ = fmaxf(mt_, __shfl_xor(mt_, 32));
      float mn = fmaxf(mrow[qb], mt_);
      float scale = __expf(mrow[qb] - mn);
      mrow[qb] = mn;
      float ssum = 0.f;
#pragma unroll
      for (int kb = 0; kb < 4; ++kb) {
        f32x4 p;
        p.x = __expf(s[kb].x - mn); p.y = __expf(s[kb].y - mn);
        p.z = __expf(s[kb].z - mn); p.w = __expf(s[kb].w - mn);
        ssum += (p.x + p.y) + (p.z + p.w);
        uint2 pp; pp.x = pack2(p.x, p.y); pp.y = pack2(p.z, p.w);
        int c16 = 2 * kb + (g >> 1);
        *(uint2*)&Pl[w][qq * 64 + ((c16 ^ (qq & 7)) * 8) + (g & 1) * 4] = pp;
      }
      srow[qb] = srow[qb] * scale + ssum;
#pragma unroll
      for (int db = 0; db < 2; ++db) {
        oacc[db][qb].x *= scale; oacc[db][qb].y *= scale;
        oacc[db][qb].z *= scale; oacc[db][qb].w *= scale;
      }
    }
    // this wave's P writes -> visible to its own cross-lane reads
    asm volatile("s_waitcnt lgkmcnt(0)" ::: "memory");

    // ---- PV: O^T[d][q] += sum_k V^T[d][k] * P[q][k]; V direct from global ----
#pragma unroll
    for (int ks = 0; ks < 2; ++ks) {
      short8 vf[2], pf[2];
#pragma unroll
      for (int qb = 0; qb < 2; ++qb) {
        int qq = qb * 16 + ql;
        pf[qb] = *(const short8*)&Pl[w][qq * 64 + (((ks * 4 + g) ^ (qq & 7)) * 8)];
      }
#pragma unroll
      for (int db = 0; db < 2; ++db)
        vf[db] = *(const short8*)&Vtb[(size_t)(bb * 256 + h * 32 + db * 16 + ql) * 2048 + k0 + ks * 32 + 8 * g];
#pragma unroll
      for (int db = 0; db < 2; ++db)
#pragma unroll
        for (int qb = 0; qb < 2; ++qb)
          oacc[db][qb] = __builtin_amdgcn_mfma_f32_16x16x32_bf16(vf[db], pf[qb], oacc[db][qb], 0, 0, 0);
    }
  }

  // ---- epilogue ----
#pragma unroll
  for (int qb = 0; qb < 2; ++qb) {
    float s_ = srow[qb];
    s_ += __shfl_xor(s_, 16);
    s_ += __shfl_xor(s_, 32);
    int qq = qb * 16 + ql;
    if (NHALF == 1) {
      float rinv = 1.0f / s_;
#pragma unroll
      for (int db = 0; db < 2; ++db) {
        f32x4 v = oacc[db][qb];
        uint2 pv2;
        pv2.x = pack2(v.x * rinv, v.y * rinv);
        pv2.y = pack2(v.z * rinv, v.w * rinv);
        *(uint2*)&Ab[(size_t)(bb * TB + q0 + qq) * 256 + h * 32 + db * 16 + 4 * g] = pv2;
      }
    } else {
      // unnormalized partial O (bf16) + (m, s)
#pragma unroll
      for (int db = 0; db < 2; ++db) {
        f32x4 v = oacc[db][qb];
        uint2 pv2;
        pv2.x = pack2(v.x, v.y);
        pv2.y = pack2(v.z, v.w);
        *(uint2*)&Op[(size_t)((half * 4 + bb) * TB + q0 + qq) * 256 + h * 32 + db * 16 + 4 * g] = pv2;
      }
      if (g == 0) {
        float2 ms; ms.x = mrow[qb]; ms.y = s_;
        MS[(size_t)((half * 4 + bb) * TB + q0 + qq) * 8 + h] = ms;
      }
    }
  }
}

// ---------------- kernel 3b: merge split-K partials ----------------
__global__ __launch_bounds__(256) void k_merge(
    const unsigned short* __restrict__ Op, const float2* __restrict__ MS,
    unsigned short* __restrict__ Ab) {
  int idx = blockIdx.x * 256 + threadIdx.x;  // 65536 = 4*2048*8 (bbq, h)
  int bbq = idx >> 3;
  int h = idx & 7;
  float2 ms0 = MS[(size_t)bbq * 8 + h];
  float2 ms1 = MS[(size_t)(4 * TB + bbq) * 8 + h];
  float m = fmaxf(ms0.x, ms1.x);
  float sc0 = ms0.y > 0.f ? __expf(ms0.x - m) : 0.f;
  float sc1 = ms1.y > 0.f ? __expf(ms1.x - m) : 0.f;
  float s = ms0.y * sc0 + ms1.y * sc1;
  float rinv = 1.0f / s;
  sc0 *= rinv; sc1 *= rinv;
  const uint4* p0 = (const uint4*)&Op[(size_t)bbq * 256 + h * 32];
  const uint4* p1 = (const uint4*)&Op[(size_t)(4 * TB + bbq) * 256 + h * 32];
  uint4* po = (uint4*)&Ab[(size_t)bbq * 256 + h * 32];
#pragma unroll
  for (int c = 0; c < 4; ++c) {
    uint4 a = p0[c], b = p1[c], o;
    const unsigned* ap = (const unsigned*)&a;
    const unsigned* bp = (const unsigned*)&b;
    unsigned* op = (unsigned*)&o;
#pragma unroll
    for (int j = 0; j < 4; ++j) {
      float alo = bf2f((unsigned short)(ap[j] & 0xffff));
      float ahi = bf2f((unsigned short)(ap[j] >> 16));
      float blo = bf2f((unsigned short)(bp[j] & 0xffff));
      float bhi = bf2f((unsigned short)(bp[j] >> 16));
      op[j] = pack2(alo * sc0 + blo * sc1, ahi * sc0 + bhi * sc1);
    }
    po[c] = o;
  }
}

// ---------------- kernel 4: output projection ----------------
__global__ __launch_bounds__(256, 2) void k_oproj(
    const unsigned short* __restrict__ Ab, const float* __restrict__ Wo,
    const float* __restrict__ bo, float* __restrict__ out) {
  __shared__ unsigned short Al[64 * 256];
  __shared__ unsigned short Bl[64 * 256];
  const int m0 = blockIdx.x * 64, n0 = blockIdx.y * 64;
  const int tid = threadIdx.x;
#pragma unroll
  for (int it = 0; it < 8; ++it) {
    int C = it * 256 + tid;
    int row = C >> 5, lc = C & 31;
    uint4 va = *(const uint4*)&Ab[(size_t)(m0 + row) * 256 + lc * 8];
    *(uint4*)&Al[row * 256 + ((lc ^ (row & 7)) * 8)] = va;
    const float4* gb = (const float4*)(Wo + (size_t)(n0 + row) * 256 + lc * 8);
    float4 b0 = gb[0], b1 = gb[1];
    uint4 pb;
    pb.x = pack2(b0.x, b0.y); pb.y = pack2(b0.z, b0.w);
    pb.z = pack2(b1.x, b1.y); pb.w = pack2(b1.z, b1.w);
    *(uint4*)&Bl[row * 256 + ((lc ^ (row & 7)) * 8)] = pb;
  }
  __syncthreads();

  const int w = tid >> 6, l = tid & 63, g = l >> 4, ql = l & 15;
  const int wm = w >> 1, wn = w & 1;
  f32x4 acc[2][2] = {};
#pragma unroll
  for (int kk = 0; kk < 8; ++kk) {
    short8 af[2], bf_[2];
#pragma unroll
    for (int mi = 0; mi < 2; ++mi) {
      int row = wm * 32 + mi * 16 + ql;
      af[mi] = *(const short8*)&Al[row * 256 + (((kk * 4 + g) ^ (row & 7)) * 8)];
    }
#pragma unroll
    for (int ni = 0; ni < 2; ++ni) {
      int row = wn * 32 + ni * 16 + ql;
      bf_[ni] = *(const short8*)&Bl[row * 256 + (((kk * 4 + g) ^ (row & 7)) * 8)];
    }
#pragma unroll
    for (int mi = 0; mi < 2; ++mi)
#pragma unroll
      for (int ni = 0; ni < 2; ++ni)
        acc[mi][ni] = __builtin_amdgcn_mfma_f32_16x16x32_bf16(af[mi], bf_[ni], acc[mi][ni], 0, 0, 0);
  }
#pragma unroll
  for (int ni = 0; ni < 2; ++ni) {
    int n = n0 + wn * 32 + ni * 16 + ql;
    float bs = bo[n];
#pragma unroll
    for (int mi = 0; mi < 2; ++mi) {
      int mb = m0 + wm * 32 + mi * 16 + 4 * g;
      out[(size_t)(mb + 0) * 256 + n] = acc[mi][ni].x + bs;
      out[(size_t)(mb + 1) * 256 + n] = acc[mi][ni].y + bs;
      out[(size_t)(mb + 2) * 256 + n] = acc[mi][ni].z + bs;
      out[(size_t)(mb + 3) * 256 + n] = acc[mi][ni].w + bs;
    }
  }
}

extern "C" void kernel_launch(void* const* d_in, const int* in_sizes, int n_in,
                              void* d_out, int out_size, void* d_ws, size_t ws_size,
                              hipStream_t stream) {
  const float* x    = (const float*)d_in[0];
  const float* oc   = (const float*)d_in[1];
  const float* Wq   = (const float*)d_in[2];
  const float* bq   = (const float*)d_in[3];
  const float* Wk   = (const float*)d_in[4];
  const float* bk   = (const float*)d_in[5];
  const float* Wv   = (const float*)d_in[6];
  const float* bv   = (const float*)d_in[7];
  const float* Wo   = (const float*)d_in[8];
  const float* bo   = (const float*)d_in[9];
  const float* eta  = (const float*)d_in[10];
  const float* beta = (const float*)d_in[11];
  const float* alpha= (const float*)d_in[12];

  const size_t NE = (size_t)8192 * 256;  // elements per [B*T, 256] bf16 buffer
  unsigned short* Qb  = (unsigned short*)d_ws;
  unsigned short* Kb  = Qb + NE;
  unsigned short* Vtb = Kb + NE;
  unsigned short* Ab  = Vtb + NE;
  float* td = (float*)(Ab + NE);
  unsigned short* Op = (unsigned short*)(td + TB);
  float2* MS = (float2*)(Op + 2 * NE);
  float* out = (float*)d_out;

  // bytes needed for split path: 4 bf16 bufs + td + 2 partial O + 2 MS
  size_t need = 4 * NE * 2 + TB * 4 + 2 * NE * 2 + (size_t)2 * 4 * TB * 8 * 8;
  bool split = ws_size >= need;

  k_tables<<<dim3(8), dim3(256), 0, stream>>>(eta, beta, alpha, td);
  k_proj<<<dim3(128, 4, 3), dim3(256), 0, stream>>>(x, Wq, bq, Wk, bk, Wv, bv, Qb, Kb, Vtb);
  if (split) {
    k_attn<2><<<dim3(128, 4), dim3(512), 0, stream>>>(Qb, Kb, Vtb, oc, td, Op, MS, Ab);
    k_merge<<<dim3(256), dim3(256), 0, stream>>>(Op, MS, Ab);
  } else {
    k_attn<1><<<dim3(64, 4), dim3(512), 0, stream>>>(Qb, Kb, Vtb, oc, td, Op, MS, Ab);
  }
  k_oproj<<<dim3(128, 4), dim3(256), 0, stream>>>(Ab, Wo, bo, out);
}